// Round 5
// baseline (477.972 us; speedup 1.0000x reference)
//
#include <hip/hip_runtime.h>
#include <hip/hip_bf16.h>

// Problem constants (fixed by the reference)
constexpr int BATCH  = 32;
constexpr int TIME   = 1024;
constexpr int IN_DIM = 512;
constexpr int HIDDEN = 512;

constexpr int GM = BATCH * TIME;   // 32768  (GEMM M)
constexpr int GN = HIDDEN;         // 512    (GEMM N)
constexpr int GK = IN_DIM;         // 512    (GEMM K)

#define GLOBAL_AS __attribute__((address_space(1)))
#define LDS_AS    __attribute__((address_space(3)))

// s_waitcnt immediate: vmcnt[3:0]|expcnt(no-wait)|lgkmcnt(no-wait)|vmcnt[5:4]
#define WAITCNT_VMCNT(n) (((n) & 15) | (((n) >> 4) << 14) | (0x7 << 4) | (0xF << 8))

// ---------------- Phase 1: fp32 SGEMM with bias ----------------
// 128x128x16 tile, 256 threads, 8x8 microtile.
// R4 analysis: with BOTH A and B staged through LDS, the CU-shared LDS pipe
// (64 ds_read_b128/wave/tile x 16 waves/CU) saturates at the same ~110-160us
// as the FMA issue rate -> 252us plateau. Fix: B panel is only 256 KB per
// N-tile and shared by all 256 M-blocks -> read B fragments DIRECTLY from
// global (L2-resident, 256B contiguous per wave-read); only A goes through
// LDS (it needs the k-major transpose). Halves LDS traffic, one barrier/tile.
// VGPR discipline (R2/R3 lessons): no min-occupancy bound, no DMA for A.
constexpr int BM = 128;
constexpr int BN = 128;
constexpr int BK = 16;
constexpr int LDAs = BM + 4;   // A^T in LDS, padded (2-way alias only = free)

__global__ __launch_bounds__(256) void sgemm_bias_kernel(
    const float* __restrict__ A,     // [GM, GK]
    const float* __restrict__ B,     // [GK, GN]
    const float* __restrict__ bias,  // [GN]
    float* __restrict__ C)           // [GM, GN]
{
    __shared__ __align__(16) float As[2][BK * LDAs];   // 16.9 KB total

    const int tid = threadIdx.x;           // 0..255
    // blockIdx.x = M-tile (256), blockIdx.y = N-tile (4): same-A blocks are
    // 256 apart in linear id -> same XCD under round-robin -> A L2 reuse.
    const int bm  = blockIdx.x * BM;
    const int bn  = blockIdx.y * BN;

    // wave-quadrant mapping: wave w covers a 64x64 quadrant; lanes form an
    // 8x8 grid inside it.
    const int w    = tid >> 6;
    const int lane = tid & 63;
    const int row0 = (w >> 1) * 64 + (lane >> 3) * 8;
    const int col0 = (w & 1)  * 64 + (lane & 7)  * 8;

    // per-thread A global-load coordinates (two float4 quads)
    const int ar0 = tid >> 2;              // A row for quad 0 (0..63), +64
    const int ac  = (tid & 3) << 2;        // A col within K-tile (0..12)

    float4 va0, va1;
    auto load_a = [&](int k0) {
        va0 = *reinterpret_cast<const float4*>(A + (size_t)(bm + ar0) * GK + k0 + ac);
        va1 = *reinterpret_cast<const float4*>(A + (size_t)(bm + ar0 + 64) * GK + k0 + ac);
    };
    auto store_a = [&](float* asp) {
        asp[(ac + 0) * LDAs + ar0] = va0.x;
        asp[(ac + 1) * LDAs + ar0] = va0.y;
        asp[(ac + 2) * LDAs + ar0] = va0.z;
        asp[(ac + 3) * LDAs + ar0] = va0.w;
        asp[(ac + 0) * LDAs + ar0 + 64] = va1.x;
        asp[(ac + 1) * LDAs + ar0 + 64] = va1.y;
        asp[(ac + 2) * LDAs + ar0 + 64] = va1.z;
        asp[(ac + 3) * LDAs + ar0 + 64] = va1.w;
    };

    float acc[8][8];
    #pragma unroll
    for (int i = 0; i < 8; ++i)
        #pragma unroll
        for (int j = 0; j < 8; ++j) acc[i][j] = 0.0f;

    load_a(0);

    constexpr int NTILES = GK / BK;        // 32
    #pragma unroll 1
    for (int it = 0; it < NTILES; ++it) {
        const int p = it & 1;
        float* asp = As[p];

        // stage prefetched A regs into LDS buffer p; write->barrier->read of
        // the same buffer is 2 iterations (and one barrier) apart => safe
        // with a single barrier per tile.
        store_a(asp);
        __syncthreads();

        // issue next tile's A loads (land during this tile's compute)
        if (it + 1 < NTILES) load_a((it + 1) * BK);

        // B fragments straight from global (L2-hot); distance-1 prefetch.
        const float* Brow = B + (size_t)(it * BK) * GN + bn + col0;
        float4 b0 = *reinterpret_cast<const float4*>(Brow);
        float4 b1 = *reinterpret_cast<const float4*>(Brow + 4);

        #pragma unroll
        for (int kk = 0; kk < BK; ++kk) {
            float4 nb0, nb1;
            if (kk + 1 < BK) {
                nb0 = *reinterpret_cast<const float4*>(Brow + (kk + 1) * GN);
                nb1 = *reinterpret_cast<const float4*>(Brow + (kk + 1) * GN + 4);
            }
            const float4 a0 = *reinterpret_cast<const float4*>(&asp[kk * LDAs + row0]);
            const float4 a1 = *reinterpret_cast<const float4*>(&asp[kk * LDAs + row0 + 4]);
            const float arr[8] = {a0.x, a0.y, a0.z, a0.w, a1.x, a1.y, a1.z, a1.w};
            const float brr[8] = {b0.x, b0.y, b0.z, b0.w, b1.x, b1.y, b1.z, b1.w};
            #pragma unroll
            for (int i = 0; i < 8; ++i)
                #pragma unroll
                for (int j = 0; j < 8; ++j)
                    acc[i][j] = fmaf(arr[i], brr[j], acc[i][j]);
            b0 = nb0; b1 = nb1;
        }
    }

    // ---- epilogue: add bias (separate fp32 add, like numpy), store ----
    #pragma unroll
    for (int i = 0; i < 8; ++i) {
        const size_t r = (size_t)(bm + row0 + i);
        #pragma unroll
        for (int j = 0; j < 8; j += 4) {
            float4 v;
            v.x = __fadd_rn(acc[i][j + 0], bias[bn + col0 + j + 0]);
            v.y = __fadd_rn(acc[i][j + 1], bias[bn + col0 + j + 1]);
            v.z = __fadd_rn(acc[i][j + 2], bias[bn + col0 + j + 2]);
            v.w = __fadd_rn(acc[i][j + 3], bias[bn + col0 + j + 3]);
            *reinterpret_cast<float4*>(&C[r * GN + bn + col0 + j]) = v;
        }
    }
}

// ---------------- Phase 2: LIF scan, producer/consumer v3 ----------------
// R4 lesson: 64 blocks = 64 CUs caps per-CU VMEM issue at ~1.5 TB/s total.
// v3: 256 blocks (one per CU), 64 h-columns each. One width-16 DMA covers
// FOUR timesteps (lane i -> t + i/16, cols (i%16)*4..+3): per-lane global
// addrs are free-form; only the LDS side must be base + lane*16. Ring = 256
// t-slots (64 KB). vmcnt(16) retirement -> 16 KB in flight per block x 256
// blocks = 4 MB outstanding (>= HBM BW*latency product). Consumer wave: one
// (s,v) chain per lane from LDS, coalesced 256B stores.
constexpr int SH   = 64;               // h-columns per block
constexpr int SCH  = 16;               // timesteps per chunk
constexpr int NCHK = TIME / SCH;       // 64 chunks
constexpr int RT   = 256;              // ring capacity in t-slots (64 KB)
constexpr int RCH  = RT / SCH;         // 16 ring chunks

__global__ __launch_bounds__(128) void lif_scan_kernel(
    const float* __restrict__ I,   // [B, T, H]
    float* __restrict__ O)         // [B, T, H]
{
    __shared__ __align__(16) float ring[RT * SH];   // 64 KB
    __shared__ int prod_c;                 // chunks fully landed in LDS
    __shared__ int cons_c;                 // chunks consumed

    const int blk  = blockIdx.x;           // 0..255
    const int b    = blk >> 3;             // 8 blocks per batch row
    const int h0   = (blk & 7) * SH;
    const int wave = threadIdx.x >> 6;
    const int lane = threadIdx.x & 63;
    const size_t base0 = (size_t)b * TIME * HIDDEN + h0;

    if (threadIdx.x == 0) { prod_c = 0; cons_c = 0; }
    __syncthreads();

    if (wave == 0) {
        // ---------------- producer ----------------
        // lane i reads I[t + i/16][h0 + (i%16)*4 .. +3]  (16 B)
        const float* g0 = I + base0 + (size_t)(lane >> 4) * HIDDEN + (lane & 15) * 4;
        #pragma unroll 1
        for (int c = 0; c < NCHK; ++c) {
            if (c >= RCH) {   // ring slot reuse: chunk c-RCH must be consumed
                while (__hip_atomic_load(&cons_c, __ATOMIC_ACQUIRE,
                                         __HIP_MEMORY_SCOPE_WORKGROUP)
                       < c - RCH + 1) { }
            }
            const int slot = (c & (RCH - 1)) * SCH;
            #pragma unroll
            for (int u = 0; u < 4; ++u) {   // 4 DMAs x 4 timesteps each
                __builtin_amdgcn_global_load_lds(
                    (GLOBAL_AS const void*)(g0 + (size_t)(c * SCH + u * 4) * HIDDEN),
                    (LDS_AS void*)&ring[(slot + u * 4) * SH], 16, 0, 0);
            }
            // newest 16 DMAs = chunks c..c-3  =>  chunks <= c-4 have landed
            __builtin_amdgcn_s_waitcnt(WAITCNT_VMCNT(16));
            if (c >= 4)
                __hip_atomic_store(&prod_c, c - 3, __ATOMIC_RELEASE,
                                   __HIP_MEMORY_SCOPE_WORKGROUP);
        }
        __builtin_amdgcn_s_waitcnt(WAITCNT_VMCNT(0));
        __hip_atomic_store(&prod_c, NCHK, __ATOMIC_RELEASE,
                           __HIP_MEMORY_SCOPE_WORKGROUP);
    } else {
        // ---------------- consumer: 1 chain per lane ----------------
        // exp(-0.05), exp(-0.2) correctly rounded fp32 (match np.exp)
        const float am = 0.95122942450071400910f;
        const float as = 0.81873075307798185867f;
        float v = 0.0f, s = 0.0f;
        float* o0 = O + base0 + lane;

        #pragma unroll 1
        for (int c = 0; c < NCHK; ++c) {
            while (__hip_atomic_load(&prod_c, __ATOMIC_ACQUIRE,
                                     __HIP_MEMORY_SCOPE_WORKGROUP) < c + 1) { }
            const int slot = (c & (RCH - 1)) * SCH;
            float ob[SCH];
            #pragma unroll
            for (int u = 0; u < SCH; ++u) {
                const float x = ring[(slot + u) * SH + lane];
                // separate mul/add roundings to match numpy (no FMA fusion)
                s = __fadd_rn(__fmul_rn(as, s), x);
                v = __fadd_rn(__fmul_rn(am, v), s);
                const float o = (v > 1.0f) ? 1.0f : 0.0f;
                v = __fsub_rn(v, o);
                ob[u] = o;
            }
            #pragma unroll
            for (int u = 0; u < SCH; ++u)
                o0[(size_t)(c * SCH + u) * HIDDEN] = ob[u];
            __hip_atomic_store(&cons_c, c + 1, __ATOMIC_RELEASE,
                               __HIP_MEMORY_SCOPE_WORKGROUP);
        }
    }
}

extern "C" void kernel_launch(void* const* d_in, const int* in_sizes, int n_in,
                              void* d_out, int out_size, void* d_ws, size_t ws_size,
                              hipStream_t stream) {
    const float* spikes = (const float*)d_in[0];   // [32, 1024, 512]
    const float* W      = (const float*)d_in[1];   // [512, 512]
    const float* bias   = (const float*)d_in[2];   // [512]
    float* out  = (float*)d_out;                   // [32, 1024, 512]
    float* I_in = (float*)d_ws;                    // 64 MiB scratch

    dim3 g1(GM / BM, GN / BN);                     // (256, 4)
    sgemm_bias_kernel<<<g1, 256, 0, stream>>>(spikes, W, bias, I_in);

    lif_scan_kernel<<<BATCH * HIDDEN / SH, 128, 0, stream>>>(I_in, out);
}

// Round 6
// 307.011 us; speedup vs baseline: 1.5569x; 1.5569x over previous
//
#include <hip/hip_runtime.h>
#include <hip/hip_bf16.h>

// Problem constants (fixed by the reference)
constexpr int BATCH  = 32;
constexpr int TIME   = 1024;
constexpr int IN_DIM = 512;
constexpr int HIDDEN = 512;

constexpr int GM = BATCH * TIME;   // 32768  (GEMM M)
constexpr int GN = HIDDEN;         // 512    (GEMM N)
constexpr int GK = IN_DIM;         // 512    (GEMM K)

#define GLOBAL_AS __attribute__((address_space(1)))
#define LDS_AS    __attribute__((address_space(3)))

// s_waitcnt immediate: vmcnt[3:0]|expcnt(no-wait)|lgkmcnt(no-wait)|vmcnt[5:4]
#define WAITCNT_VMCNT(n) (((n) & 15) | (((n) >> 4) << 14) | (0x7 << 4) | (0xF << 8))
#define COMPILER_FENCE() asm volatile("" ::: "memory")

// ---------------- Phase 1: fp32 SGEMM with bias ----------------
// 128x128x16, 256 threads, 8x8 microtile, BOTH operands via LDS.
// Measured ranking across rounds: this two-barrier body (R1: 238us) beats
// reg-double-buffer single-barrier (R4: 252us), async-DMA pipeline (R3:
// 385us, VGPR 180 occupancy collapse), B-from-global (R5: 385us, L2-latency
// serialization in k-loop). Cross-block TLP (4 blocks/CU) hides the
// barrier/latency here. Block mapping from R4: same-A blocks 256 apart in
// linear id -> same XCD -> FETCH 138->123 MB.
// VGPR discipline: plain __launch_bounds__(256); no min-occupancy (R2: cap
// spilled the 64-float acc -> 4.5 GB scratch traffic).
constexpr int BM = 128;
constexpr int BN = 128;
constexpr int BK = 16;
constexpr int LDAs = BM + 4;   // padded (2-way LDS alias only = free)
constexpr int LDBs = BN + 4;

__global__ __launch_bounds__(256) void sgemm_bias_kernel(
    const float* __restrict__ A,     // [GM, GK]
    const float* __restrict__ B,     // [GK, GN]
    const float* __restrict__ bias,  // [GN]
    float* __restrict__ C)           // [GM, GN]
{
    __shared__ __align__(16) float As[BK * LDAs];
    __shared__ __align__(16) float Bs[BK * LDBs];

    const int tid = threadIdx.x;           // 0..255
    const int bm  = blockIdx.x * BM;       // M-tile (256 of them)
    const int bn  = blockIdx.y * BN;       // N-tile (4)

    // wave-quadrant mapping: wave w covers a 64x64 quadrant; lanes form an
    // 8x8 grid inside it -> LDS frag reads are 2-way aliased (free).
    const int w    = tid >> 6;
    const int lane = tid & 63;
    const int row0 = (w >> 1) * 64 + (lane >> 3) * 8;
    const int col0 = (w & 1)  * 64 + (lane & 7)  * 8;

    // per-thread global-load coordinates (two float4 quads each for A and B)
    const int ar0 = tid >> 2;              // A row for quad 0 (0..63), +64
    const int ac  = (tid & 3) << 2;        // A col within K-tile (0..12)
    const int br0 = tid >> 5;              // B row for quad 0 (0..7), +8
    const int bc  = (tid & 31) << 2;       // B col within N-tile (0..124)

    float acc[8][8];
    #pragma unroll
    for (int i = 0; i < 8; ++i)
        #pragma unroll
        for (int j = 0; j < 8; ++j) acc[i][j] = 0.0f;

    #pragma unroll 1
    for (int k0 = 0; k0 < GK; k0 += BK) {
        // ---- global loads to registers ----
        float4 va0 = *reinterpret_cast<const float4*>(A + (size_t)(bm + ar0) * GK + k0 + ac);
        float4 va1 = *reinterpret_cast<const float4*>(A + (size_t)(bm + ar0 + 64) * GK + k0 + ac);
        float4 vb0 = *reinterpret_cast<const float4*>(B + (size_t)(k0 + br0) * GN + bn + bc);
        float4 vb1 = *reinterpret_cast<const float4*>(B + (size_t)(k0 + br0 + 8) * GN + bn + bc);

        __syncthreads();   // previous tile's compute done before overwrite

        As[(ac + 0) * LDAs + ar0] = va0.x;
        As[(ac + 1) * LDAs + ar0] = va0.y;
        As[(ac + 2) * LDAs + ar0] = va0.z;
        As[(ac + 3) * LDAs + ar0] = va0.w;
        As[(ac + 0) * LDAs + ar0 + 64] = va1.x;
        As[(ac + 1) * LDAs + ar0 + 64] = va1.y;
        As[(ac + 2) * LDAs + ar0 + 64] = va1.z;
        As[(ac + 3) * LDAs + ar0 + 64] = va1.w;
        *reinterpret_cast<float4*>(&Bs[br0 * LDBs + bc]) = vb0;
        *reinterpret_cast<float4*>(&Bs[(br0 + 8) * LDBs + bc]) = vb1;

        __syncthreads();

        // ---- compute 16 k-steps ----
        #pragma unroll
        for (int kk = 0; kk < BK; ++kk) {
            const float4 a0 = *reinterpret_cast<const float4*>(&As[kk * LDAs + row0]);
            const float4 a1 = *reinterpret_cast<const float4*>(&As[kk * LDAs + row0 + 4]);
            const float4 b0 = *reinterpret_cast<const float4*>(&Bs[kk * LDBs + col0]);
            const float4 b1 = *reinterpret_cast<const float4*>(&Bs[kk * LDBs + col0 + 4]);
            const float arr[8] = {a0.x, a0.y, a0.z, a0.w, a1.x, a1.y, a1.z, a1.w};
            const float brr[8] = {b0.x, b0.y, b0.z, b0.w, b1.x, b1.y, b1.z, b1.w};
            #pragma unroll
            for (int i = 0; i < 8; ++i)
                #pragma unroll
                for (int j = 0; j < 8; ++j)
                    acc[i][j] = fmaf(arr[i], brr[j], acc[i][j]);
        }
    }

    // ---- epilogue: add bias (separate fp32 add, like numpy), store ----
    #pragma unroll
    for (int i = 0; i < 8; ++i) {
        const size_t r = (size_t)(bm + row0 + i);
        #pragma unroll
        for (int j = 0; j < 8; j += 4) {
            float4 v;
            v.x = __fadd_rn(acc[i][j + 0], bias[bn + col0 + j + 0]);
            v.y = __fadd_rn(acc[i][j + 1], bias[bn + col0 + j + 1]);
            v.z = __fadd_rn(acc[i][j + 2], bias[bn + col0 + j + 2]);
            v.w = __fadd_rn(acc[i][j + 3], bias[bn + col0 + j + 3]);
            *reinterpret_cast<float4*>(&C[r * GN + bn + col0 + j]) = v;
        }
    }
}

// ---------------- Phase 2: LIF scan, producer/consumer v4 ----------------
// R3/R4/R5 all plateaued at ~90us (1.4 TB/s) because the RELEASE atomic
// store of the progress flag made the compiler emit s_waitcnt vmcnt(0)
// before it -- draining ALL in-flight DMAs every chunk (~4KB outstanding,
// matching the measured 5.5 GB/s/block). v4: RELAXED atomics; ordering is
// enforced by our manual s_waitcnt vmcnt(16) + compiler-only fences. Same
// 256-block width-16-DMA structure as v3.
constexpr int SH   = 64;               // h-columns per block
constexpr int SCH  = 16;               // timesteps per chunk
constexpr int NCHK = TIME / SCH;       // 64 chunks
constexpr int RT   = 256;              // ring capacity in t-slots (64 KB)
constexpr int RCH  = RT / SCH;         // 16 ring chunks

__global__ __launch_bounds__(128) void lif_scan_kernel(
    const float* __restrict__ I,   // [B, T, H]
    float* __restrict__ O)         // [B, T, H]
{
    __shared__ __align__(16) float ring[RT * SH];   // 64 KB
    __shared__ int prod_c;                 // chunks fully landed in LDS
    __shared__ int cons_c;                 // chunks consumed

    const int blk  = blockIdx.x;           // 0..255
    const int b    = blk >> 3;             // 8 blocks per batch row
    const int h0   = (blk & 7) * SH;
    const int wave = threadIdx.x >> 6;
    const int lane = threadIdx.x & 63;
    const size_t base0 = (size_t)b * TIME * HIDDEN + h0;

    if (threadIdx.x == 0) { prod_c = 0; cons_c = 0; }
    __syncthreads();

    if (wave == 0) {
        // ---------------- producer ----------------
        // lane i covers t = c*16 + u*4 + i/16, h = h0 + (i%16)*4 .. +3 (16B)
        const float* g0 = I + base0 + (size_t)(lane >> 4) * HIDDEN + (lane & 15) * 4;
        #pragma unroll 1
        for (int c = 0; c < NCHK; ++c) {
            if (c >= RCH) {   // ring slot reuse: chunk c-RCH must be consumed
                while (__hip_atomic_load(&cons_c, __ATOMIC_RELAXED,
                                         __HIP_MEMORY_SCOPE_WORKGROUP)
                       < c - RCH + 1) { }
                COMPILER_FENCE();
            }
            const int slot = (c & (RCH - 1)) * SCH;
            #pragma unroll
            for (int u = 0; u < 4; ++u) {   // 4 DMAs x 4 timesteps each
                __builtin_amdgcn_global_load_lds(
                    (GLOBAL_AS const void*)(g0 + (size_t)(c * SCH + u * 4) * HIDDEN),
                    (LDS_AS void*)&ring[(slot + u * 4) * SH], 16, 0, 0);
            }
            COMPILER_FENCE();
            // allow 16 outstanding = chunks c..c-3  =>  <= c-4 have landed
            __builtin_amdgcn_s_waitcnt(WAITCNT_VMCNT(16));
            COMPILER_FENCE();
            if (c >= 4)
                __hip_atomic_store(&prod_c, c - 3, __ATOMIC_RELAXED,
                                   __HIP_MEMORY_SCOPE_WORKGROUP);
        }
        COMPILER_FENCE();
        __builtin_amdgcn_s_waitcnt(WAITCNT_VMCNT(0));
        COMPILER_FENCE();
        __hip_atomic_store(&prod_c, NCHK, __ATOMIC_RELAXED,
                           __HIP_MEMORY_SCOPE_WORKGROUP);
    } else {
        // ---------------- consumer: 1 chain per lane ----------------
        // exp(-0.05), exp(-0.2) correctly rounded fp32 (match np.exp)
        const float am = 0.95122942450071400910f;
        const float as = 0.81873075307798185867f;
        float v = 0.0f, s = 0.0f;
        float* o0 = O + base0 + lane;

        #pragma unroll 1
        for (int c = 0; c < NCHK; ++c) {
            while (__hip_atomic_load(&prod_c, __ATOMIC_RELAXED,
                                     __HIP_MEMORY_SCOPE_WORKGROUP) < c + 1) { }
            COMPILER_FENCE();
            const int slot = (c & (RCH - 1)) * SCH;
            float ob[SCH];
            #pragma unroll
            for (int u = 0; u < SCH; ++u) {
                const float x = ring[(slot + u) * SH + lane];
                // separate mul/add roundings to match numpy (no FMA fusion)
                s = __fadd_rn(__fmul_rn(as, s), x);
                v = __fadd_rn(__fmul_rn(am, v), s);
                const float o = (v > 1.0f) ? 1.0f : 0.0f;
                v = __fsub_rn(v, o);
                ob[u] = o;
            }
            COMPILER_FENCE();   // ring values consumed into regs before publish
            __hip_atomic_store(&cons_c, c + 1, __ATOMIC_RELAXED,
                               __HIP_MEMORY_SCOPE_WORKGROUP);
            #pragma unroll
            for (int u = 0; u < SCH; ++u)
                o0[(size_t)(c * SCH + u) * HIDDEN] = ob[u];
        }
    }
}

extern "C" void kernel_launch(void* const* d_in, const int* in_sizes, int n_in,
                              void* d_out, int out_size, void* d_ws, size_t ws_size,
                              hipStream_t stream) {
    const float* spikes = (const float*)d_in[0];   // [32, 1024, 512]
    const float* W      = (const float*)d_in[1];   // [512, 512]
    const float* bias   = (const float*)d_in[2];   // [512]
    float* out  = (float*)d_out;                   // [32, 1024, 512]
    float* I_in = (float*)d_ws;                    // 64 MiB scratch

    dim3 g1(GM / BM, GN / BN);                     // (256, 4)
    sgemm_bias_kernel<<<g1, 256, 0, stream>>>(spikes, W, bias, I_in);

    lif_scan_kernel<<<BATCH * HIDDEN / SH, 128, 0, stream>>>(I_in, out);
}